// Round 12
// baseline (335.757 us; speedup 1.0000x reference)
//
#include <hip/hip_runtime.h>

#define B_ 32
#define C_ 128
#define H_ 32
#define W_ 32
#define WN 63
#define O_ 512              // 4*C
#define HTB (33 * 256)      // bytes per hT buffer
#define HTB2 (2 * HTB)      // bytes per batch (2 buffers)
#define BIAS_ROW 32768      // shared bias row index in is_ws

typedef __attribute__((ext_vector_type(8))) short bf16x8;
typedef __attribute__((ext_vector_type(4))) float f32x4;
typedef __attribute__((ext_vector_type(4))) unsigned short us4;
typedef __attribute__((ext_vector_type(2))) unsigned int u32x2;

#define L2E 1.442695041f
#define L2E2 2.885390082f

#if __has_builtin(__builtin_amdgcn_exp2f)
__device__ __forceinline__ float EXP2(float x) { return __builtin_amdgcn_exp2f(x); }
#else
__device__ __forceinline__ float EXP2(float x) {
  float r; asm("v_exp_f32 %0, %1" : "=v"(r) : "v"(x)); return r;
}
#endif

__device__ __forceinline__ unsigned cvt_pk_bf16(float lo, float hi) {
  unsigned r;
  asm("v_cvt_pk_bf16_f32 %0, %1, %2" : "=v"(r) : "v"(lo), "v"(hi));
  return r;
}

__device__ __forceinline__ unsigned short f2bf(float f) {
  union { float f; unsigned u; } v; v.f = f;
  unsigned r = v.u + 0x7FFFu + ((v.u >> 16) & 1u);
  return (unsigned short)(r >> 16);
}
__device__ __forceinline__ float bf2f(unsigned short h) {
  union { unsigned u; float f; } v; v.u = ((unsigned)h) << 16;
  return v.f;
}

// LDS-only barrier (no vmcnt drain).
__device__ __forceinline__ void lds_barrier() {
  __builtin_amdgcn_sched_barrier(0);
  asm volatile("s_waitcnt lgkmcnt(0)" ::: "memory");
  __builtin_amdgcn_s_barrier();
  __builtin_amdgcn_sched_barrier(0);
}

// Diagonal-packed layout: step t's rows j in [jmin, jmax] contiguous at
// row = b*1024 + diag_off(t) + (j - jmin). Row = 512 u16 (1KB): i_s gates
// (prescaled incl. biases); after step t the scan overwrites bytes [0,512)
// of consumed rows with the f32 h outputs.
__device__ __forceinline__ int diag_off(int t) {
  return (t <= 31) ? (t * (t + 1) / 2) : (1024 - (63 - t) * (64 - t) / 2);
}

// ---------------------------------------------------------------------------
// Kernel 1: per (b, jq) block computes i_s for 4 j-rows (512x128 GEMM, K=128).
// ---------------------------------------------------------------------------
__global__ __launch_bounds__(512, 2)
void is_kernel(const float* __restrict__ x, const float* __restrict__ W_is,
               const float* __restrict__ b_is, const float* __restrict__ b_ss,
               unsigned short* __restrict__ is_ws) {
  const int bid = blockIdx.x;
  const int b = bid >> 3, jq = bid & 7;
  const int tid = threadIdx.x;
  const int w = tid >> 6, l = tid & 63;
  const int lg = l >> 4, lm = l & 15;

  // shared bias row (block 0 only): (b_is+b_ss)*SC
  if (bid == 0) {
    float v = (b_is[tid] + b_ss[tid]) * ((tid >> 7) == 3 ? L2E2 : L2E);
    is_ws[(size_t)BIAS_ROW * O_ + tid] = f2bf(v);
  }

  // xT: rows rr = jl*32 + c (128 rows) x 128 ch bf16, 16B-chunk swizzle by rr&15
  __shared__ __align__(16) unsigned short xT[128 * 128];
#pragma unroll
  for (int it = 0; it < 32; ++it) {
    int idx = it * 512 + tid;
    int c = idx & 31, jl = (idx >> 5) & 3, ch = idx >> 7;
    float v = x[((b * C_ + ch) * H_ + jq * 4 + jl) * W_ + c];
    int rr = jl * 32 + c;
    int byteCol = ch * 2;
    int addr = rr * 256 + (((byteCol >> 4) ^ (rr & 15)) << 4) + (byteCol & 15);
    *(unsigned short*)((char*)xT + addr) = f2bf(v);
  }
  __syncthreads();

  f32x4 acc[4][8];
#pragma unroll
  for (int g = 0; g < 4; ++g)
#pragma unroll
    for (int nt = 0; nt < 8; ++nt) acc[g][nt] = (f32x4){0.f, 0.f, 0.f, 0.f};

#pragma unroll
  for (int kf = 0; kf < 4; ++kf) {
    bf16x8 bfv[8];
#pragma unroll
    for (int nt = 0; nt < 8; ++nt) {
      int rr = (nt >> 1) * 32 + (nt & 1) * 16 + lm;
      int chunk = kf * 4 + lg;
      int addr = rr * 256 + ((chunk ^ (rr & 15)) << 4);
      bfv[nt] = *(const bf16x8*)((const char*)xT + addr);
    }
#pragma unroll
    for (int g = 0; g < 4; ++g) {
      const int o = g * 128 + 16 * w + lm;
      const float* wp = W_is + o * C_ + kf * 32 + lg * 8;
      f32x4 wa = *(const f32x4*)(wp);
      f32x4 wb = *(const f32x4*)(wp + 4);
      bf16x8 af;
      af[0] = (short)f2bf(wa[0]); af[1] = (short)f2bf(wa[1]);
      af[2] = (short)f2bf(wa[2]); af[3] = (short)f2bf(wa[3]);
      af[4] = (short)f2bf(wb[0]); af[5] = (short)f2bf(wb[1]);
      af[6] = (short)f2bf(wb[2]); af[7] = (short)f2bf(wb[3]);
#pragma unroll
      for (int nt = 0; nt < 8; ++nt)
        acc[g][nt] = __builtin_amdgcn_mfma_f32_16x16x32_bf16(af, bfv[nt], acc[g][nt], 0, 0, 0);
    }
  }

#pragma unroll
  for (int g = 0; g < 4; ++g) {
    const float sc = (g == 3) ? L2E2 : L2E;
    const int ob = g * 128 + 16 * w + lg * 4;
#pragma unroll
    for (int nt = 0; nt < 8; ++nt) {
      int jl = nt >> 1;
      int c = (nt & 1) * 16 + lm;
      int j = jq * 4 + jl;
      int t = j + c;
      int jmin = (t > 31) ? (t - 31) : 0;
      us4 st;
#pragma unroll
      for (int r = 0; r < 4; ++r)
        st[r] = f2bf((acc[g][nt][r] + b_is[ob + r] + b_ss[ob + r]) * sc);
      *(us4*)(is_ws + (size_t)(b * 1024 + diag_off(t) + (j - jmin)) * O_ + ob) = st;
    }
  }
}

// ---------------------------------------------------------------------------
// Kernel 2: diagonal scan, TWO batches per block (ILP over TLP). 16 blocks x
// 512 threads (8 waves, weights shared across both chains). Per step:
// b0-GEMM -> b0-cell (overlappable with b1-GEMM, independent) -> b1-GEMM ->
// b1-cell -> ONE lds_barrier. Single acc array reused b0->b1 to stay inside
// the 256-reg/wave budget at 2 waves/SIMD.
// ---------------------------------------------------------------------------
__global__ __launch_bounds__(512, 2)
void scan_kernel(const float* __restrict__ Wss,
                 unsigned short* __restrict__ is_ws) {
  const int b0 = blockIdx.x * 2;
  const int tid = threadIdx.x;
  const int w = tid >> 6, l = tid & 63;
  const int lg = l >> 4, lm = l & 15;
  const int chW = 16 * w;
  float* ows = (float*)is_ws;

  // hT[batch][buf][33][128] bf16, swizzled; row 32 = permanent zero row.
  __shared__ __align__(16) unsigned short hT[2 * 2 * 33 * 128];
  for (int i = tid; i < 2 * 2 * 33 * 128; i += 512) hT[i] = 0;

  // Recurrent weights [W0|W1], prescaled: A[g][kf], kf<4 -> W0 (h_up)
  bf16x8 A[4][8];
#pragma unroll
  for (int g = 0; g < 4; ++g) {
    const float sc = (g == 3) ? L2E2 : L2E;
    const int o = g * 128 + chW + lm;
#pragma unroll
    for (int kf = 0; kf < 4; ++kf) {
      const int ch = kf * 32 + lg * 8;
      const float* wp = Wss + (o * C_ + ch) * 2;  // interleaved (W0,W1)
      f32x4 q0 = *(const f32x4*)(wp + 0);
      f32x4 q1 = *(const f32x4*)(wp + 4);
      f32x4 q2 = *(const f32x4*)(wp + 8);
      f32x4 q3 = *(const f32x4*)(wp + 12);
      bf16x8 a0, a1;
      a0[0] = (short)f2bf(q0[0] * sc); a1[0] = (short)f2bf(q0[1] * sc);
      a0[1] = (short)f2bf(q0[2] * sc); a1[1] = (short)f2bf(q0[3] * sc);
      a0[2] = (short)f2bf(q1[0] * sc); a1[2] = (short)f2bf(q1[1] * sc);
      a0[3] = (short)f2bf(q1[2] * sc); a1[3] = (short)f2bf(q1[3] * sc);
      a0[4] = (short)f2bf(q2[0] * sc); a1[4] = (short)f2bf(q2[1] * sc);
      a0[5] = (short)f2bf(q2[2] * sc); a1[5] = (short)f2bf(q2[3] * sc);
      a0[6] = (short)f2bf(q3[0] * sc); a1[6] = (short)f2bf(q3[1] * sc);
      a0[7] = (short)f2bf(q3[2] * sc); a1[7] = (short)f2bf(q3[3] * sc);
      A[g][kf] = a0;
      A[g][kf + 4] = a1;
    }
  }

  float cst0[2][4] = {{0.f, 0.f, 0.f, 0.f}, {0.f, 0.f, 0.f, 0.f}};
  float cst1[2][4] = {{0.f, 0.f, 0.f, 0.f}, {0.f, 0.f, 0.f, 0.f}};

  __syncthreads();

  // One batch's step: GEMM (acc fresh) -> cell (z = acc + isv) -> writes.
  auto half_step = [&](int t, int nLo, int rowBase, int batOff, int rOff,
                       int wOff, us4 (&isv)[4][2], float (&cst)[2][4]) {
    f32x4 acc[4][2];
#pragma unroll
    for (int n = 0; n < 2; ++n) {
      if (n >= nLo) {
#pragma unroll
        for (int g = 0; g < 4; ++g) acc[g][n] = (f32x4){0.f, 0.f, 0.f, 0.f};
        const int j = n * 16 + lm;
        const int rU = (j == 0) ? 32 : j - 1;
#pragma unroll
        for (int kf = 0; kf < 8; ++kf) {
          const int rr = (kf < 4) ? rU : j;
          const int chunk = (kf & 3) * 4 + lg;
          const int addr = batOff + rOff + rr * 256 + ((chunk ^ (rr & 15)) << 4);
          bf16x8 bfv = *(const bf16x8*)((const char*)hT + addr);
#pragma unroll
          for (int g = 0; g < 4; ++g)
            acc[g][n] = __builtin_amdgcn_mfma_f32_16x16x32_bf16(A[g][kf], bfv, acc[g][n], 0, 0, 0);
        }
      }
    }

#pragma unroll
    for (int n = 0; n < 2; ++n) {
      if (n >= nLo) {
        const int j = n * 16 + lm;
        const int c = t - j;
        const bool inband = ((unsigned)c < 32u);
        f32x4 ov;
#pragma unroll
        for (int r = 0; r < 4; ++r) {
          float zo = acc[0][n][r] + bf2f(isv[0][n][r]);
          float zf = acc[1][n][r] + bf2f(isv[1][n][r]);
          float zi = acc[2][n][r] + bf2f(isv[2][n][r]);
          float zg = acc[3][n][r] + bf2f(isv[3][n][r]);
          float eo = EXP2(-zo);
          float ef = EXP2(-zf);
          float ei = EXP2(-zi);
          float eg = EXP2(-zg);
          float Af = 1.f + ef, Bi = 1.f + ei, Gg = 1.f + eg;
          float BG = Bi * Gg;
          float num = cst[n][r] * BG + (1.f - eg) * Af;
          float cn = num * __builtin_amdgcn_rcpf(Af * BG);
          cst[n][r] = cn;
          float ec = EXP2(cn * -L2E2);
          float hn = (1.f - ec) * __builtin_amdgcn_rcpf((1.f + ec) * (1.f + eo));
          ov[r] = hn;
        }
        // h -> bf16 into the WRITE hT buffer first (shortens path to barrier)
        u32x2 hb;
        hb[0] = cvt_pk_bf16(ov[0], ov[1]);
        hb[1] = cvt_pk_bf16(ov[2], ov[3]);
        const int byteCol = chW * 2 + lg * 8;
        const int chunk = byteCol >> 4;
        const int addr = batOff + wOff + j * 256 + ((chunk ^ (j & 15)) << 4) + (byteCol & 15);
        *(u32x2*)((char*)hT + addr) = hb;
        // diag-packed f32 h output into the consumed is row
        if (inband)
          *(f32x4*)(ows + (size_t)(rowBase + j) * 256 + chW + lg * 4) = ov;
      }
    }
  };

  auto load_is = [&](int rowBase, us4 (&iv)[4][2], int t, int nLo) {
#pragma unroll
    for (int n = 0; n < 2; ++n) {
      if (n >= nLo) {
        const int j = n * 16 + lm;
        const bool valid = ((unsigned)(t - j) < 32u);
        const int row = valid ? (rowBase + j) : BIAS_ROW;
        const unsigned short* p = is_ws + (size_t)row * O_ + chW + lg * 4;
#pragma unroll
        for (int g = 0; g < 4; ++g) iv[g][n] = *(const us4*)(p + g * 128);
      }
    }
  };

  auto step_body = [&](int t, int rOff, int wOff) {
    const int nLo = (t < 47) ? 0 : 1;  // rows j<16 dead once t-31 > 15
    const int jminT = (t > 31) ? (t - 31) : 0;
    const int rowBase0 = b0 * 1024 + diag_off(t) - jminT;
    const int rowBase1 = rowBase0 + 1024;

    // issue both batches' i_s loads up front (consumed late in each cell)
    us4 isv0[4][2], isv1[4][2];
    load_is(rowBase0, isv0, t, nLo);
    load_is(rowBase1, isv1, t, nLo);

    half_step(t, nLo, rowBase0, 0,    rOff, wOff, isv0, cst0);
    half_step(t, nLo, rowBase1, HTB2, rOff, wOff, isv1, cst1);

    lds_barrier();
  };

  for (int t = 0; t < WN - 1; t += 2) {
    step_body(t, 0, HTB);
    step_body(t + 1, HTB, 0);
  }
  step_body(WN - 1, 0, HTB);
}

// ---------------------------------------------------------------------------
// Kernel 3: unpack diag-packed f32 h rows -> out[b][ch][j][c].
// ---------------------------------------------------------------------------
__global__ __launch_bounds__(256, 4)
void unpack_kernel(const float* __restrict__ ows, float* __restrict__ out) {
  const int bid = blockIdx.x;  // b*32 + j
  const int b = bid >> 5, j = bid & 31;
  const int tid = threadIdx.x;

  __shared__ float tile[32 * 129];  // [c][ch], pad 129 vs bank conflicts

  {
    const int ch = tid & 127;
    const int half = tid >> 7;  // 2 rows per pass
#pragma unroll
    for (int q = 0; q < 16; ++q) {
      int c = q * 2 + half;
      int t = j + c;
      int jmin = (t > 31) ? (t - 31) : 0;
      size_t row = (size_t)(b * 1024 + diag_off(t) + (j - jmin));
      tile[c * 129 + ch] = ows[row * 256 + ch];
    }
  }
  __syncthreads();

  {
    const int c = tid & 31;
    const int ch0 = tid >> 5;  // 0..7
#pragma unroll
    for (int q = 0; q < 16; ++q) {
      int ch = q * 8 + ch0;
      out[((size_t)(b * C_ + ch) * H_ + j) * W_ + c] = tile[c * 129 + ch];
    }
  }
}

// ---------------------------------------------------------------------------
extern "C" void kernel_launch(void* const* d_in, const int* in_sizes, int n_in,
                              void* d_out, int out_size, void* d_ws, size_t ws_size,
                              hipStream_t stream) {
  const float* x    = (const float*)d_in[0];
  const float* W_is = (const float*)d_in[1];
  const float* b_is = (const float*)d_in[2];
  const float* W_ss = (const float*)d_in[3];
  const float* b_ss = (const float*)d_in[4];
  float* out = (float*)d_out;
  unsigned short* is_ws = (unsigned short*)d_ws;  // 32 MiB diag rows + bias row

  is_kernel<<<dim3(B_ * 8), dim3(512), 0, stream>>>(x, W_is, b_is, b_ss, is_ws);
  scan_kernel<<<dim3(B_ / 2), dim3(512), 0, stream>>>(W_ss, is_ws);
  unpack_kernel<<<dim3(B_ * H_), dim3(256), 0, stream>>>((const float*)is_ws, out);
}

// Round 13
// 176.935 us; speedup vs baseline: 1.8976x; 1.8976x over previous
//
#include <hip/hip_runtime.h>

#define B_ 32
#define C_ 128
#define H_ 32
#define W_ 32
#define WN 63
#define O_ 512              // 4*C
#define HTB (33 * 256)      // bytes per hT buffer
#define BIAS_ROW 32768      // shared bias row index in is_ws

typedef __attribute__((ext_vector_type(8))) short bf16x8;
typedef __attribute__((ext_vector_type(4))) float f32x4;
typedef __attribute__((ext_vector_type(2))) float f32x2;
typedef __attribute__((ext_vector_type(4))) unsigned short us4;
typedef __attribute__((ext_vector_type(2))) unsigned int u32x2;

#define L2E 1.442695041f
#define L2E2 2.885390082f

#if __has_builtin(__builtin_amdgcn_exp2f)
__device__ __forceinline__ float EXP2(float x) { return __builtin_amdgcn_exp2f(x); }
#else
__device__ __forceinline__ float EXP2(float x) {
  float r; asm("v_exp_f32 %0, %1" : "=v"(r) : "v"(x)); return r;
}
#endif

__device__ __forceinline__ unsigned cvt_pk_bf16(float lo, float hi) {
  unsigned r;
  asm("v_cvt_pk_bf16_f32 %0, %1, %2" : "=v"(r) : "v"(lo), "v"(hi));
  return r;
}

__device__ __forceinline__ unsigned short f2bf(float f) {
  union { float f; unsigned u; } v; v.f = f;
  unsigned r = v.u + 0x7FFFu + ((v.u >> 16) & 1u);
  return (unsigned short)(r >> 16);
}
__device__ __forceinline__ float bf2f(unsigned short h) {
  union { unsigned u; float f; } v; v.u = ((unsigned)h) << 16;
  return v.f;
}

// LDS-only barrier (no vmcnt drain).
__device__ __forceinline__ void lds_barrier() {
  __builtin_amdgcn_sched_barrier(0);
  asm volatile("s_waitcnt lgkmcnt(0)" ::: "memory");
  __builtin_amdgcn_s_barrier();
  __builtin_amdgcn_sched_barrier(0);
}

// Diagonal-packed layout: step t's rows j in [jmin, jmax] contiguous at
// row = b*1024 + diag_off(t) + (j - jmin). Row = 512 u16 (1KB): i_s gates
// (prescaled incl. biases); after step t the scan overwrites bytes [0,512)
// of consumed rows with the f32 h outputs.
__device__ __forceinline__ int diag_off(int t) {
  return (t <= 31) ? (t * (t + 1) / 2) : (1024 - (63 - t) * (64 - t) / 2);
}

// ---------------------------------------------------------------------------
// Kernel 1: per (b, jq) block computes i_s for 4 j-rows (512x128 GEMM, K=128).
// ---------------------------------------------------------------------------
__global__ __launch_bounds__(512, 2)
void is_kernel(const float* __restrict__ x, const float* __restrict__ W_is,
               const float* __restrict__ b_is, const float* __restrict__ b_ss,
               unsigned short* __restrict__ is_ws) {
  const int bid = blockIdx.x;
  const int b = bid >> 3, jq = bid & 7;
  const int tid = threadIdx.x;
  const int w = tid >> 6, l = tid & 63;
  const int lg = l >> 4, lm = l & 15;

  // shared bias row (block 0 only): (b_is+b_ss)*SC
  if (bid == 0) {
    float v = (b_is[tid] + b_ss[tid]) * ((tid >> 7) == 3 ? L2E2 : L2E);
    is_ws[(size_t)BIAS_ROW * O_ + tid] = f2bf(v);
  }

  // xT: rows rr = jl*32 + c (128 rows) x 128 ch bf16, 16B-chunk swizzle by rr&15
  __shared__ __align__(16) unsigned short xT[128 * 128];
#pragma unroll
  for (int it = 0; it < 32; ++it) {
    int idx = it * 512 + tid;
    int c = idx & 31, jl = (idx >> 5) & 3, ch = idx >> 7;
    float v = x[((b * C_ + ch) * H_ + jq * 4 + jl) * W_ + c];
    int rr = jl * 32 + c;
    int byteCol = ch * 2;
    int addr = rr * 256 + (((byteCol >> 4) ^ (rr & 15)) << 4) + (byteCol & 15);
    *(unsigned short*)((char*)xT + addr) = f2bf(v);
  }
  __syncthreads();

  f32x4 acc[4][8];
#pragma unroll
  for (int g = 0; g < 4; ++g)
#pragma unroll
    for (int nt = 0; nt < 8; ++nt) acc[g][nt] = (f32x4){0.f, 0.f, 0.f, 0.f};

#pragma unroll
  for (int kf = 0; kf < 4; ++kf) {
    bf16x8 bfv[8];
#pragma unroll
    for (int nt = 0; nt < 8; ++nt) {
      int rr = (nt >> 1) * 32 + (nt & 1) * 16 + lm;
      int chunk = kf * 4 + lg;
      int addr = rr * 256 + ((chunk ^ (rr & 15)) << 4);
      bfv[nt] = *(const bf16x8*)((const char*)xT + addr);
    }
#pragma unroll
    for (int g = 0; g < 4; ++g) {
      const int o = g * 128 + 16 * w + lm;
      const float* wp = W_is + o * C_ + kf * 32 + lg * 8;
      f32x4 wa = *(const f32x4*)(wp);
      f32x4 wb = *(const f32x4*)(wp + 4);
      bf16x8 af;
      af[0] = (short)f2bf(wa[0]); af[1] = (short)f2bf(wa[1]);
      af[2] = (short)f2bf(wa[2]); af[3] = (short)f2bf(wa[3]);
      af[4] = (short)f2bf(wb[0]); af[5] = (short)f2bf(wb[1]);
      af[6] = (short)f2bf(wb[2]); af[7] = (short)f2bf(wb[3]);
#pragma unroll
      for (int nt = 0; nt < 8; ++nt)
        acc[g][nt] = __builtin_amdgcn_mfma_f32_16x16x32_bf16(af, bfv[nt], acc[g][nt], 0, 0, 0);
    }
  }

#pragma unroll
  for (int g = 0; g < 4; ++g) {
    const float sc = (g == 3) ? L2E2 : L2E;
    const int ob = g * 128 + 16 * w + lg * 4;
#pragma unroll
    for (int nt = 0; nt < 8; ++nt) {
      int jl = nt >> 1;
      int c = (nt & 1) * 16 + lm;
      int j = jq * 4 + jl;
      int t = j + c;
      int jmin = (t > 31) ? (t - 31) : 0;
      us4 st;
#pragma unroll
      for (int r = 0; r < 4; ++r)
        st[r] = f2bf((acc[g][nt][r] + b_is[ob + r] + b_ss[ob + r]) * sc);
      *(us4*)(is_ws + (size_t)(b * 1024 + diag_off(t) + (j - jmin)) * O_ + ob) = st;
    }
  }
}

// ---------------------------------------------------------------------------
// Kernel 2: diagonal scan. 32 blocks, 512 threads (8 waves). Wave w: channels
// [16w,16w+16), M-tiles {w,w+8,w+16,w+24} = gates o,f,i,g. Cell math packed
// on f32x2 pairs (v_pk_* full-rate); trans scalar. s_setprio(1) around MFMA.
// ---------------------------------------------------------------------------
__global__ __launch_bounds__(512, 2)
void scan_kernel(const float* __restrict__ Wss,
                 unsigned short* __restrict__ is_ws) {
  const int b = blockIdx.x;
  const int tid = threadIdx.x;
  const int w = tid >> 6, l = tid & 63;
  const int lg = l >> 4, lm = l & 15;
  const int chW = 16 * w;
  float* ows = (float*)is_ws;  // f32 view for diag-packed h output rows

  __shared__ __align__(16) unsigned short hT[2 * 33 * 128];
  for (int i = tid; i < 2 * 33 * 128; i += 512) hT[i] = 0;

  // Recurrent weights [W0|W1], prescaled: A[g][kf], kf<4 -> W0 (h_up)
  bf16x8 A[4][8];
#pragma unroll
  for (int g = 0; g < 4; ++g) {
    const float sc = (g == 3) ? L2E2 : L2E;
    const int o = g * 128 + chW + lm;
#pragma unroll
    for (int kf = 0; kf < 4; ++kf) {
      const int ch = kf * 32 + lg * 8;
      const float* wp = Wss + (o * C_ + ch) * 2;  // interleaved (W0,W1)
      f32x4 q0 = *(const f32x4*)(wp + 0);
      f32x4 q1 = *(const f32x4*)(wp + 4);
      f32x4 q2 = *(const f32x4*)(wp + 8);
      f32x4 q3 = *(const f32x4*)(wp + 12);
      bf16x8 a0, a1;
      a0[0] = (short)f2bf(q0[0] * sc); a1[0] = (short)f2bf(q0[1] * sc);
      a0[1] = (short)f2bf(q0[2] * sc); a1[1] = (short)f2bf(q0[3] * sc);
      a0[2] = (short)f2bf(q1[0] * sc); a1[2] = (short)f2bf(q1[1] * sc);
      a0[3] = (short)f2bf(q1[2] * sc); a1[3] = (short)f2bf(q1[3] * sc);
      a0[4] = (short)f2bf(q2[0] * sc); a1[4] = (short)f2bf(q2[1] * sc);
      a0[5] = (short)f2bf(q2[2] * sc); a1[5] = (short)f2bf(q2[3] * sc);
      a0[6] = (short)f2bf(q3[0] * sc); a1[6] = (short)f2bf(q3[1] * sc);
      a0[7] = (short)f2bf(q3[2] * sc); a1[7] = (short)f2bf(q3[3] * sc);
      A[g][kf] = a0;
      A[g][kf + 4] = a1;
    }
  }

  float cst[2][4] = {{0.f, 0.f, 0.f, 0.f}, {0.f, 0.f, 0.f, 0.f}};
  us4 isvA[4][2], isvB[4][2];

  auto load_is = [&](int t, us4 (&iv)[4][2]) {
    const int jmin = (t > 31) ? (t - 31) : 0;
    const int dOff = b * 1024 + diag_off(t) - jmin;
#pragma unroll
    for (int n = 0; n < 2; ++n) {
      const int j = n * 16 + lm;
      const bool valid = ((unsigned)(t - j) < 32u);
      const int row = valid ? (dOff + j) : BIAS_ROW;
      const unsigned short* p = is_ws + (size_t)row * O_ + chW + lg * 4;
#pragma unroll
      for (int g = 0; g < 4; ++g) iv[g][n] = *(const us4*)(p + g * 128);
    }
  };

  auto step_body = [&](int t, int rOff, int wOff, us4 (&isv)[4][2],
                       us4 (&isvN)[4][2], bool pf) {
    const int nLo = (t < 47) ? 0 : 1;  // rows j<16 dead once t-31 > 15
    const int jminT = (t > 31) ? (t - 31) : 0;
    const int rowBase = b * 1024 + diag_off(t) - jminT;

    f32x4 acc[4][2];
#pragma unroll
    for (int n = 0; n < 2; ++n) {
      if (n >= nLo) {
#pragma unroll
        for (int g = 0; g < 4; ++g)
#pragma unroll
          for (int r = 0; r < 4; ++r) acc[g][n][r] = bf2f(isv[g][n][r]);
        const int j = n * 16 + lm;
        const int rU = (j == 0) ? 32 : j - 1;
        __builtin_amdgcn_s_setprio(1);
#pragma unroll
        for (int kf = 0; kf < 8; ++kf) {
          const int rr = (kf < 4) ? rU : j;
          const int chunk = (kf & 3) * 4 + lg;
          const int addr = rOff + rr * 256 + ((chunk ^ (rr & 15)) << 4);
          bf16x8 bfv = *(const bf16x8*)((const char*)hT + addr);
#pragma unroll
          for (int g = 0; g < 4; ++g)
            acc[g][n] = __builtin_amdgcn_mfma_f32_16x16x32_bf16(A[g][kf], bfv, acc[g][n], 0, 0, 0);
        }
        __builtin_amdgcn_s_setprio(0);
      }
    }

    if (pf) load_is(t + 1, isvN);

#pragma unroll
    for (int n = 0; n < 2; ++n) {
      if (n >= nLo) {
        const int j = n * 16 + lm;
        const int c = t - j;
        const bool inband = ((unsigned)c < 32u);
        f32x4 ov;
        // cell math on f32x2 pairs -> v_pk_* full-rate; trans scalar.
#pragma unroll
        for (int p = 0; p < 2; ++p) {
          f32x2 zo = {acc[0][n][2 * p], acc[0][n][2 * p + 1]};
          f32x2 zf = {acc[1][n][2 * p], acc[1][n][2 * p + 1]};
          f32x2 zi = {acc[2][n][2 * p], acc[2][n][2 * p + 1]};
          f32x2 zg = {acc[3][n][2 * p], acc[3][n][2 * p + 1]};
          f32x2 eo = {EXP2(-zo[0]), EXP2(-zo[1])};
          f32x2 ef = {EXP2(-zf[0]), EXP2(-zf[1])};
          f32x2 ei = {EXP2(-zi[0]), EXP2(-zi[1])};
          f32x2 eg = {EXP2(-zg[0]), EXP2(-zg[1])};
          f32x2 one = {1.f, 1.f};
          f32x2 Af = one + ef, Bi = one + ei, Gg = one + eg;
          f32x2 BG = Bi * Gg;
          f32x2 cprev = {cst[n][2 * p], cst[n][2 * p + 1]};
          f32x2 num = cprev * BG + (one - eg) * Af;
          f32x2 den = Af * BG;
          f32x2 rden = {__builtin_amdgcn_rcpf(den[0]), __builtin_amdgcn_rcpf(den[1])};
          f32x2 cn = num * rden;
          cst[n][2 * p] = cn[0];
          cst[n][2 * p + 1] = cn[1];
          f32x2 ecm = cn * (f32x2){-L2E2, -L2E2};
          f32x2 ec = {EXP2(ecm[0]), EXP2(ecm[1])};
          f32x2 t1 = (one + ec) * (one + eo);
          f32x2 rt = {__builtin_amdgcn_rcpf(t1[0]), __builtin_amdgcn_rcpf(t1[1])};
          f32x2 hn = (one - ec) * rt;
          ov[2 * p] = hn[0];
          ov[2 * p + 1] = hn[1];
        }
        // h -> bf16 into the WRITE hT buffer first (shortest path to barrier)
        u32x2 hb;
        hb[0] = cvt_pk_bf16(ov[0], ov[1]);
        hb[1] = cvt_pk_bf16(ov[2], ov[3]);
        const int byteCol = chW * 2 + lg * 8;
        const int chunk = byteCol >> 4;
        const int addr = wOff + j * 256 + ((chunk ^ (j & 15)) << 4) + (byteCol & 15);
        *(u32x2*)((char*)hT + addr) = hb;
        // diag-packed f32 h output into the consumed is row
        if (inband)
          *(f32x4*)(ows + (size_t)(rowBase + j) * 256 + chW + lg * 4) = ov;
      }
    }

    lds_barrier();
  };

  load_is(0, isvA);
  __syncthreads();

  for (int t = 0; t < WN - 1; t += 2) {
    step_body(t, 0, HTB, isvA, isvB, true);
    step_body(t + 1, HTB, 0, isvB, isvA, t + 2 < WN);
  }
  step_body(WN - 1, 0, HTB, isvA, isvB, false);
}

// ---------------------------------------------------------------------------
// Kernel 3: unpack diag-packed f32 h rows -> out[b][ch][j][c].
// ---------------------------------------------------------------------------
__global__ __launch_bounds__(256, 4)
void unpack_kernel(const float* __restrict__ ows, float* __restrict__ out) {
  const int bid = blockIdx.x;  // b*32 + j
  const int b = bid >> 5, j = bid & 31;
  const int tid = threadIdx.x;

  __shared__ float tile[32 * 129];  // [c][ch], pad 129 vs bank conflicts

  {
    const int ch = tid & 127;
    const int half = tid >> 7;  // 2 rows per pass
#pragma unroll
    for (int q = 0; q < 16; ++q) {
      int c = q * 2 + half;
      int t = j + c;
      int jmin = (t > 31) ? (t - 31) : 0;
      size_t row = (size_t)(b * 1024 + diag_off(t) + (j - jmin));
      tile[c * 129 + ch] = ows[row * 256 + ch];
    }
  }
  __syncthreads();

  {
    const int c = tid & 31;
    const int ch0 = tid >> 5;  // 0..7
#pragma unroll
    for (int q = 0; q < 16; ++q) {
      int ch = q * 8 + ch0;
      out[((size_t)(b * C_ + ch) * H_ + j) * W_ + c] = tile[c * 129 + ch];
    }
  }
}

// ---------------------------------------------------------------------------
extern "C" void kernel_launch(void* const* d_in, const int* in_sizes, int n_in,
                              void* d_out, int out_size, void* d_ws, size_t ws_size,
                              hipStream_t stream) {
  const float* x    = (const float*)d_in[0];
  const float* W_is = (const float*)d_in[1];
  const float* b_is = (const float*)d_in[2];
  const float* W_ss = (const float*)d_in[3];
  const float* b_ss = (const float*)d_in[4];
  float* out = (float*)d_out;
  unsigned short* is_ws = (unsigned short*)d_ws;  // 32 MiB diag rows + bias row

  is_kernel<<<dim3(B_ * 8), dim3(512), 0, stream>>>(x, W_is, b_is, b_ss, is_ws);
  scan_kernel<<<dim3(B_), dim3(512), 0, stream>>>(W_ss, is_ws);
  unpack_kernel<<<dim3(B_ * H_), dim3(256), 0, stream>>>((const float*)is_ws, out);
}